// Round 7
// baseline (321.253 us; speedup 1.0000x reference)
//
#include <hip/hip_runtime.h>
#include <hip/hip_bf16.h>
#include <math.h>

typedef float  f32x4  __attribute__((ext_vector_type(4)));
typedef short  bf16x4 __attribute__((ext_vector_type(4)));
typedef __bf16 bfv4   __attribute__((ext_vector_type(4)));

#define B_    16
#define S_    4096
#define D_    256
#define CK_   16                 // chunk length
#define NC_   (S_ / CK_)         // 256 chunks
#define NP_   (NC_ / 2)          // 128 fused pairs (32-row superchunks)
#define PBLOB_ 1664              // 512 Taa + 512 Tbb + 512 Tba (bf16) + 64 ca + 64 cb (f32)
#define W_    4                  // waves per main block (column split, 64 cols each)

// ---------------- helpers
__device__ __forceinline__ f32x4 mfma_bf16(bf16x4 a, bf16x4 b, f32x4 c) {
#if defined(__has_builtin) && __has_builtin(__builtin_amdgcn_mfma_f32_16x16x16bf16_1k)
    return __builtin_amdgcn_mfma_f32_16x16x16bf16_1k(a, b, c, 0, 0, 0);
#else
    f32x4 d;
    asm("v_mfma_f32_16x16x16_bf16 %0, %1, %2, %3" : "=v"(d) : "v"(a), "v"(b), "v"(c));
    return d;
#endif
}
__device__ __forceinline__ bf16x4 pk4(f32x4 v) {
    bfv4 h;
    h[0] = (__bf16)v[0]; h[1] = (__bf16)v[1]; h[2] = (__bf16)v[2]; h[3] = (__bf16)v[3];
    return __builtin_bit_cast(bf16x4, h);
}
__device__ __forceinline__ f32x4 up4(bf16x4 h) {
    f32x4 r;
    r[0] = __uint_as_float(((unsigned)(unsigned short)h[0]) << 16);
    r[1] = __uint_as_float(((unsigned)(unsigned short)h[1]) << 16);
    r[2] = __uint_as_float(((unsigned)(unsigned short)h[2]) << 16);
    r[3] = __uint_as_float(((unsigned)(unsigned short)h[3]) << 16);
    return r;
}

// ---------------- prepass: one 64-thread wave per (b, pair).
// Gram blocks (hi/lo split MFMAs) assembled into a 32x32 G32 in LDS, then ONE
// 32-column forward substitution produces the EXPLICIT T32 (strict lower):
// Taa, Tbb, Tba blocks stored as bf16 A-frags. Tba = (I+Tb)*Gx*diag(ca)*(I+Ta)
// comes out of the recursion for free, letting main's fixup run da and db as
// parallel chains (no mid-chain ea -> Gx dependency).
__global__ __launch_bounds__(64) void ldm_prep(
    const float* __restrict__ x,
    const float* __restrict__ eta_raw,
    const float* __restrict__ alpha_raw,
    unsigned char* __restrict__ blob)
{
    const int lane = threadIdx.x;
    const int b = blockIdx.x >> 7;            // NP_ = 128
    const int p = blockIdx.x & (NP_ - 1);
    const int l15 = lane & 15;
    const int q   = lane >> 4;

    __shared__ float G32[1024];               // [t*32 + k], t,k in [0,32)
    __shared__ float csh[32];
    __shared__ float Ts32[1024];              // T32[t*32 + j], strict lower

    const float* xa = x + ((size_t)b * S_ + (size_t)p * 32 + l15) * D_ + q * 4;
    const float* xc = xa + 16 * D_;           // chunk b rows

    const f32x4 z = {0,0,0,0};
    f32x4 ga1=z, ga2=z, ga3=z, gb1=z, gb2=z, gb3=z, gx1=z, gx2=z, gx3=z;
    #pragma unroll 4
    for (int kb = 0; kb < 16; ++kb) {
        f32x4 va = *(const f32x4*)(xa + kb * 16);
        f32x4 vb = *(const f32x4*)(xc + kb * 16);
        bf16x4 ha = pk4(va), la = pk4(va - up4(ha));
        bf16x4 hb = pk4(vb), lb = pk4(vb - up4(hb));
        ga1 = mfma_bf16(ha, ha, ga1);
        ga2 = mfma_bf16(ha, la, ga2);
        ga3 = mfma_bf16(la, ha, ga3);
        gb1 = mfma_bf16(hb, hb, gb1);
        gb2 = mfma_bf16(hb, lb, gb2);
        gb3 = mfma_bf16(lb, hb, gb3);
        gx1 = mfma_bf16(hb, ha, gx1);         // Gx[t_b][t_a] = x_b . x_a
        gx2 = mfma_bf16(hb, la, gx2);
        gx3 = mfma_bf16(lb, ha, gx3);
    }
    f32x4 ga = (ga1 + ga2) + ga3;             // C layout: lane holds G[q*4+r][l15]
    f32x4 gb = (gb1 + gb2) + gb3;
    f32x4 gx = (gx1 + gx2) + gx3;
    // symmetric blocks: transposed store = same matrix (contiguous b128/lane)
    *(f32x4*)(&G32[l15 * 32 + q * 4]) = ga;                 // Ga at [0:16][0:16]
    *(f32x4*)(&G32[(16 + l15) * 32 + 16 + q * 4]) = gb;     // Gb at [16:32][16:32]
    // Gx not symmetric: scatter true transpose -> G32[16+t_b][t_a]
    #pragma unroll
    for (int r = 0; r < 4; ++r) G32[(16 + q * 4 + r) * 32 + l15] = gx[r];
    __syncthreads();

    const float eta   = 0.2f / (1.0f + expf(-eta_raw[0]));
    const float alpha = 0.5f + 0.5f / (1.0f + expf(-alpha_raw[0]));
    if (lane < 32) {
        float gtt = G32[lane * 33];           // diag
        float n   = fmaxf(sqrtf(gtt), 1e-6f);
        float inv = 1.0f / n;
        csh[lane] = eta * (1.0f - inv) * inv / alpha;
    }
    __syncthreads();

    if (lane < 32) {                          // 32-column forward substitution
        const int j = lane;
        float cr[32];
        #pragma unroll
        for (int k = 0; k < 32; ++k) cr[k] = csh[k];
        float Tcol[32];
        Tcol[0] = 0.f;
        #pragma unroll
        for (int t = 1; t < 32; ++t) {
            float acc = cr[j] * G32[t * 32 + j];
            #pragma unroll
            for (int k = 1; k < 31; ++k)
                if (k < t) acc += cr[k] * G32[t * 32 + k] * Tcol[k];
            Tcol[t] = (t > j) ? acc : 0.f;
        }
        #pragma unroll
        for (int t = 0; t < 32; ++t) Ts32[t * 32 + j] = Tcol[t];
    }
    __syncthreads();

    unsigned char* bp = blob + (size_t)(b * NP_ + p) * PBLOB_;
    const int idx = l15 * 16 + q * 4;
    // Taa = T32[0:16][0:16], Tbb = T32[16:32][16:32], Tba = T32[16:32][0:16]
    *(bf16x4*)(bp + idx * 2)        = pk4(*(const f32x4*)(&Ts32[l15 * 32 + q * 4]));
    *(bf16x4*)(bp + 512 + idx * 2)  = pk4(*(const f32x4*)(&Ts32[(16 + l15) * 32 + 16 + q * 4]));
    *(bf16x4*)(bp + 1024 + idx * 2) = pk4(*(const f32x4*)(&Ts32[(16 + l15) * 32 + q * 4]));
    if (lane < 32) ((float*)(bp + 1536))[lane] = csh[lane];
}

// ---------------- main scan: one 256-thread block (4 waves) per (batch, rowblk).
// Single barrier per pair at the BOTTOM of the iteration. All global loads are
// issued in the post-barrier region (X right after the parts-read/pk4, blob
// right after the old blob is consumed) so the compiler's vmcnt(0) drain at the
// next barrier finds them ~a full iteration old -> no exposed latency (this was
// the hidden ~400-600 cy/pair cost of R3/R6: loads issued just before the
// barrier were force-drained). Fixup uses explicit Taa/Tbb/Tba: da and db are
// parallel chains. Retrieval is depth-2 C-chains + add.
__global__ __launch_bounds__(256, 1) void ldm_main(
    const float* __restrict__ x,
    const float* __restrict__ Minit,
    const float* __restrict__ alpha_raw,
    const unsigned char* __restrict__ blob,
    float* __restrict__ out)
{
    const int tid    = threadIdx.x;
    const int lane   = tid & 63;
    const int w      = __builtin_amdgcn_readfirstlane(tid >> 6); // 0..3
    const int batch  = blockIdx.x >> 4;
    const int rowblk = blockIdx.x & 15;
    const int l15    = lane & 15;
    const int q      = lane >> 4;
    const int col0   = w * 64;                // wave's 64-col slice

    __shared__ f32x4 parts[2][W_][2][64];     // [parity][wave][chunk][lane] = 16 KB

    const float alpha = 0.5f + 0.5f / (1.0f + expf(-alpha_raw[0]));
    const float a2 = alpha * alpha, a4 = a2 * a2, a8 = a4 * a4, a16 = a8 * a8;
    const float a32 = a16 * a16;
    const float aq = (q == 0) ? 1.f : (q == 1) ? a4 : (q == 2) ? a8 : a8 * a4;
    const f32x4 apowA = { aq, aq * alpha, aq * a2, aq * a2 * alpha };
    const f32x4 apowB = apowA * a16;

    // identity B-fragment for transpose MFMA
    const int s = l15 - (q << 2);
    bf16x4 IB;
    IB[0] = (s == 0) ? (short)0x3F80 : (short)0;
    IB[1] = (s == 1) ? (short)0x3F80 : (short)0;
    IB[2] = (s == 2) ? (short)0x3F80 : (short)0;
    IB[3] = (s == 3) ? (short)0x3F80 : (short)0;

    const int mrow = rowblk * 16 + l15;
    f32x4 master[4];                          // 16 rows x own 64 cols
    #pragma unroll
    for (int cb = 0; cb < 4; ++cb)
        master[cb] = *(const f32x4*)(Minit + (size_t)mrow * D_ + col0 + cb * 16 + q * 4);

    const float* xbb = x + (size_t)batch * S_ * D_;
    const unsigned char* bb0 = blob + (size_t)batch * NP_ * PBLOB_;
    const int tfoff = (l15 * 16 + q * 4) * 2;

    const float* xr = xbb + (size_t)l15 * D_ + col0 + q * 4;  // row l15, own col
    float* outpj = out + (size_t)batch * S_ * D_ + rowblk * 16 + l15
                 + (size_t)q * 4 * D_;        // chunk-a row base, pair 0

    struct BlobT { bf16x4 Ta, Tbb, Tba; f32x4 ca, cb; };
    BlobT bA, bB;
    bf16x4 Xn[8];              // bf16 A-frags of current "next" pair
    f32x4  Xf[8];              // f32 X in flight (one pair)
    bf16x4 ta[4], tb[4];       // transpose frags carried across the barrier
    const f32x4 zz = {0,0,0,0};

    {   // ---------------- prologue: pair 0 (+ pair-1 X in flight)
        #pragma unroll
        for (int cb = 0; cb < 4; ++cb) {
            Xf[cb]     = *(const f32x4*)(xr + cb * 16);
            Xf[4 + cb] = *(const f32x4*)(xr + 16 * D_ + cb * 16);
        }
        bA.Ta  = *(const bf16x4*)(bb0 + tfoff);
        bA.Tbb = *(const bf16x4*)(bb0 + 512 + tfoff);
        bA.Tba = *(const bf16x4*)(bb0 + 1024 + tfoff);
        bA.ca  = *(const f32x4*)(bb0 + 1536 + q * 16);
        bA.cb  = *(const f32x4*)(bb0 + 1600 + q * 16);
        const unsigned char* b1 = bb0 + PBLOB_;
        bB.Ta  = *(const bf16x4*)(b1 + tfoff);
        bB.Tbb = *(const bf16x4*)(b1 + 512 + tfoff);
        bB.Tba = *(const bf16x4*)(b1 + 1024 + tfoff);
        bB.ca  = *(const f32x4*)(b1 + 1536 + q * 16);
        bB.cb  = *(const f32x4*)(b1 + 1600 + q * 16);
        #pragma unroll
        for (int i = 0; i < 8; ++i) Xn[i] = pk4(Xf[i]);
        const float* x1 = xr + 32 * D_;       // X(1) in flight across barrier
        #pragma unroll
        for (int cb = 0; cb < 4; ++cb) {
            Xf[cb]     = *(const f32x4*)(x1 + cb * 16);
            Xf[4 + cb] = *(const f32x4*)(x1 + 16 * D_ + cb * 16);
        }
        // retrieval(0) + transpose frags(0)
        bf16x4 mf[4];
        #pragma unroll
        for (int cb = 0; cb < 4; ++cb) mf[cb] = pk4(master[cb]);
        f32x4 acca = mfma_bf16(Xn[1], mf[1], mfma_bf16(Xn[0], mf[0], zz))
                   + mfma_bf16(Xn[3], mf[3], mfma_bf16(Xn[2], mf[2], zz));
        f32x4 accb = mfma_bf16(Xn[5], mf[1], mfma_bf16(Xn[4], mf[0], zz))
                   + mfma_bf16(Xn[7], mf[3], mfma_bf16(Xn[6], mf[2], zz));
        parts[0][w][0][lane] = acca;
        parts[0][w][1][lane] = accb;
        #pragma unroll
        for (int cb = 0; cb < 4; ++cb) {
            ta[cb] = pk4(mfma_bf16(Xn[cb],     IB, zz));
            tb[cb] = pk4(mfma_bf16(Xn[4 + cb], IB, zz));
        }
        __syncthreads();
    }

    const float* xptr = xr + (size_t)2 * 32 * D_;        // -> X(2)
    const unsigned char* bptrE = bb0 + 2 * PBLOB_;       // even iters -> blob(j+2)
    const unsigned char* bptrO = bb0 + 3 * PBLOB_;       // odd  iters -> blob(j+2)

    auto iter = [&](int j, BlobT& bc, const unsigned char*& bptr) {
        const int par = j & 1;
        // 1. parts(j) reads issued (latency covered by 2./3.)
        f32x4 pa0 = parts[par][0][0][lane], pa1 = parts[par][1][0][lane];
        f32x4 pa2 = parts[par][2][0][lane], pa3 = parts[par][3][0][lane];
        f32x4 pb0 = parts[par][0][1][lane], pb1 = parts[par][1][1][lane];
        f32x4 pb2 = parts[par][2][1][lane], pb3 = parts[par][3][1][lane];
        // 2. convert X(j+1) (loaded last iter, drained at the barrier) to frags
        #pragma unroll
        for (int i = 0; i < 8; ++i) Xn[i] = pk4(Xf[i]);
        // 3. issue X(j+2) loads NOW -> drained at NEXT barrier (~full iter away)
        #pragma unroll
        for (int cb = 0; cb < 4; ++cb) {
            Xf[cb]     = *(const f32x4*)(xptr + cb * 16);
            Xf[4 + cb] = *(const f32x4*)(xptr + 16 * D_ + cb * 16);
        }
        if (j < NP_ - 3) xptr += 32 * D_;
        // 4. cross-wave sums
        f32x4 bba = (pa0 + pa1) + (pa2 + pa3);
        f32x4 bbb = (pb0 + pb1) + (pb2 + pb3);
        // 5. fixup: da and db are PARALLEL chains (explicit Tba)
        bf16x4 baF = pk4(bba), bbF = pk4(bbb);
        f32x4 da = mfma_bf16(bc.Ta, baF, bba);
        f32x4 db = mfma_bf16(bc.Tba, baF, mfma_bf16(bc.Tbb, bbF, bbb));
        if (w == 2) {
            #pragma unroll
            for (int r = 0; r < 4; ++r) outpj[r * D_] = da[r] * apowA[r];
        }
        if (w == 3) {
            #pragma unroll
            for (int r = 0; r < 4; ++r) outpj[(16 + r) * D_] = db[r] * apowB[r];
        }
        bf16x4 ea = pk4(da * bc.ca);
        bf16x4 eb = pk4(db * bc.cb);
        // 5.5 bc consumed -> refill with blob(j+2) (drains at next barrier)
        bc.Ta  = *(const bf16x4*)(bptr + tfoff);
        bc.Tbb = *(const bf16x4*)(bptr + 512 + tfoff);
        bc.Tba = *(const bf16x4*)(bptr + 1024 + tfoff);
        bc.ca  = *(const f32x4*)(bptr + 1536 + q * 16);
        bc.cb  = *(const f32x4*)(bptr + 1600 + q * 16);
        if (j < NP_ - 4) bptr += 2 * PBLOB_;
        // 6. rank-32 update on own cols (carried ta/tb), then *alpha^32
        #pragma unroll
        for (int cb = 0; cb < 4; ++cb) {
            f32x4 m = mfma_bf16(ta[cb], ea, master[cb]);
            master[cb] = mfma_bf16(tb[cb], eb, m) * a32;
        }
        // 7. retrieval(j+1): depth-2 chains + add
        bf16x4 mf[4];
        #pragma unroll
        for (int cb = 0; cb < 4; ++cb) mf[cb] = pk4(master[cb]);
        f32x4 acca = mfma_bf16(Xn[1], mf[1], mfma_bf16(Xn[0], mf[0], zz))
                   + mfma_bf16(Xn[3], mf[3], mfma_bf16(Xn[2], mf[2], zz));
        f32x4 accb = mfma_bf16(Xn[5], mf[1], mfma_bf16(Xn[4], mf[0], zz))
                   + mfma_bf16(Xn[7], mf[3], mfma_bf16(Xn[6], mf[2], zz));
        parts[par ^ 1][w][0][lane] = acca;
        parts[par ^ 1][w][1][lane] = accb;
        // 8. transpose frags(j+1), carried across the barrier
        #pragma unroll
        for (int cb = 0; cb < 4; ++cb) {
            ta[cb] = pk4(mfma_bf16(Xn[cb],     IB, zz));
            tb[cb] = pk4(mfma_bf16(Xn[4 + cb], IB, zz));
        }
        outpj += 32 * D_;
        // 9. barrier (vmcnt drain sees only ~iter-old loads)
        __syncthreads();
    };

    for (int j = 0; j < NP_; j += 2) {
        iter(j,     bA, bptrE);
        iter(j + 1, bB, bptrO);
    }

    // M_final -> second output region [B, D, D]
    float* Mout = out + (size_t)B_ * S_ * D_
                + ((size_t)batch * D_ + mrow) * D_;
    #pragma unroll
    for (int cb = 0; cb < 4; ++cb)
        *(f32x4*)(Mout + col0 + cb * 16 + q * 4) = master[cb];
}

extern "C" void kernel_launch(void* const* d_in, const int* in_sizes, int n_in,
                              void* d_out, int out_size, void* d_ws, size_t ws_size,
                              hipStream_t stream) {
    const float* x         = (const float*)d_in[0];
    const float* Minit     = (const float*)d_in[1];
    const float* eta_raw   = (const float*)d_in[2];
    const float* alpha_raw = (const float*)d_in[3];
    float* out = (float*)d_out;
    unsigned char* blob = (unsigned char*)d_ws;   // B_*NP_*1664 = 3.4 MB

    hipLaunchKernelGGL(ldm_prep, dim3(B_ * NP_), dim3(64), 0, stream,
                       x, eta_raw, alpha_raw, blob);
    hipLaunchKernelGGL(ldm_main, dim3(B_ * 16), dim3(256), 0, stream,
                       x, Minit, alpha_raw, blob, out);
}

// Round 8
// 271.785 us; speedup vs baseline: 1.1820x; 1.1820x over previous
//
#include <hip/hip_runtime.h>
#include <hip/hip_bf16.h>
#include <math.h>

typedef float  f32x4  __attribute__((ext_vector_type(4)));
typedef short  bf16x4 __attribute__((ext_vector_type(4)));
typedef __bf16 bfv4   __attribute__((ext_vector_type(4)));

#define B_    16
#define S_    4096
#define D_    256
#define CK_   16                 // chunk length
#define NC_   (S_ / CK_)         // 256 chunks
#define NP_   (NC_ / 2)          // 128 fused pairs (32-row superchunks)
#define PBLOB_ 1664              // 512 Ta + 512 Tb + 512 Gx (bf16) + 64 ca + 64 cb (f32)
#define W_    4                  // waves per main block (column split, 64 cols each)

// ---------------- helpers
__device__ __forceinline__ f32x4 mfma_bf16(bf16x4 a, bf16x4 b, f32x4 c) {
#if defined(__has_builtin) && __has_builtin(__builtin_amdgcn_mfma_f32_16x16x16bf16_1k)
    return __builtin_amdgcn_mfma_f32_16x16x16bf16_1k(a, b, c, 0, 0, 0);
#else
    f32x4 d;
    asm("v_mfma_f32_16x16x16_bf16 %0, %1, %2, %3" : "=v"(d) : "v"(a), "v"(b), "v"(c));
    return d;
#endif
}
__device__ __forceinline__ bf16x4 pk4(f32x4 v) {
    bfv4 h;
    h[0] = (__bf16)v[0]; h[1] = (__bf16)v[1]; h[2] = (__bf16)v[2]; h[3] = (__bf16)v[3];
    return __builtin_bit_cast(bf16x4, h);
}
__device__ __forceinline__ f32x4 up4(bf16x4 h) {
    f32x4 r;
    r[0] = __uint_as_float(((unsigned)(unsigned short)h[0]) << 16);
    r[1] = __uint_as_float(((unsigned)(unsigned short)h[1]) << 16);
    r[2] = __uint_as_float(((unsigned)(unsigned short)h[2]) << 16);
    r[3] = __uint_as_float(((unsigned)(unsigned short)h[3]) << 16);
    return r;
}

// ---------------- prepass: one 64-thread wave per (b, pair). (R1/R3/R6-verified)
// XCD map: b = blockIdx & 15 so blockIdx % 8 == b % 8 -> this pair's blob is
// written through the SAME XCD L2 that batch b's main blocks will read from.
__global__ __launch_bounds__(64) void ldm_prep(
    const float* __restrict__ x,
    const float* __restrict__ eta_raw,
    const float* __restrict__ alpha_raw,
    unsigned char* __restrict__ blob)
{
    const int lane = threadIdx.x;
    const int b = blockIdx.x & 15;            // XCD-aligned with ldm_main's batch
    const int p = blockIdx.x >> 4;            // 0..127
    const int l15 = lane & 15;
    const int q   = lane >> 4;

    __shared__ float Ga[256], Gb[256], Gxs[256];
    __shared__ float csh[32];
    __shared__ float Ts[2][256];

    const float* xa = x + ((size_t)b * S_ + (size_t)p * 32 + l15) * D_ + q * 4;
    const float* xc = xa + 16 * D_;           // chunk b rows

    const f32x4 z = {0,0,0,0};
    f32x4 ga1=z, ga2=z, ga3=z, gb1=z, gb2=z, gb3=z, gx1=z, gx2=z, gx3=z;
    #pragma unroll 4
    for (int kb = 0; kb < 16; ++kb) {
        f32x4 va = *(const f32x4*)(xa + kb * 16);
        f32x4 vb = *(const f32x4*)(xc + kb * 16);
        bf16x4 ha = pk4(va), la = pk4(va - up4(ha));
        bf16x4 hb = pk4(vb), lb = pk4(vb - up4(hb));
        ga1 = mfma_bf16(ha, ha, ga1);
        ga2 = mfma_bf16(ha, la, ga2);
        ga3 = mfma_bf16(la, ha, ga3);
        gb1 = mfma_bf16(hb, hb, gb1);
        gb2 = mfma_bf16(hb, lb, gb2);
        gb3 = mfma_bf16(lb, hb, gb3);
        gx1 = mfma_bf16(hb, ha, gx1);         // Gx[t_b][t_a] = x_b . x_a
        gx2 = mfma_bf16(hb, la, gx2);
        gx3 = mfma_bf16(lb, ha, gx3);
    }
    f32x4 ga = (ga1 + ga2) + ga3;             // C layout: lane holds G[q*4+r][l15]
    f32x4 gb = (gb1 + gb2) + gb3;
    f32x4 gx = (gx1 + gx2) + gx3;
    *(f32x4*)(&Ga[l15 * 16 + q * 4]) = ga;    // symmetric: transposed store ok
    *(f32x4*)(&Gb[l15 * 16 + q * 4]) = gb;
    #pragma unroll
    for (int r = 0; r < 4; ++r) Gxs[(q * 4 + r) * 16 + l15] = gx[r];
    __syncthreads();

    const float eta   = 0.2f / (1.0f + expf(-eta_raw[0]));
    const float alpha = 0.5f + 0.5f / (1.0f + expf(-alpha_raw[0]));
    if (lane < 32) {
        const float* G = (lane < 16) ? Ga : Gb;
        float gtt = G[l15 * 17];
        float n   = fmaxf(sqrtf(gtt), 1e-6f);
        float inv = 1.0f / n;
        csh[lane] = eta * (1.0f - inv) * inv / alpha;
    }
    __syncthreads();

    if (lane < 32) {                          // column-parallel forward substitution x2
        const int j = l15;
        const float* G  = (lane < 16) ? Ga : Gb;
        const float* cp = (lane < 16) ? csh : csh + 16;
        float cr[16];
        #pragma unroll
        for (int k = 0; k < 16; ++k) cr[k] = cp[k];
        float Tcol[16];
        Tcol[0] = 0.f;
        #pragma unroll
        for (int t = 1; t < 16; ++t) {
            float acc = cr[j] * G[t * 16 + j];
            #pragma unroll
            for (int k = 1; k < 15; ++k)
                if (k < t) acc += cr[k] * G[t * 16 + k] * Tcol[k];
            Tcol[t] = (t > j) ? acc : 0.f;
        }
        float* Tsj = Ts[lane >> 4];
        #pragma unroll
        for (int t = 0; t < 16; ++t) Tsj[t * 16 + j] = Tcol[t];
    }
    __syncthreads();

    unsigned char* bp = blob + (size_t)(b * NP_ + p) * PBLOB_;
    const int idx = l15 * 16 + q * 4;
    *(bf16x4*)(bp + idx * 2)        = pk4(*(const f32x4*)(&Ts[0][idx]));
    *(bf16x4*)(bp + 512 + idx * 2)  = pk4(*(const f32x4*)(&Ts[1][idx]));
    *(bf16x4*)(bp + 1024 + idx * 2) = pk4(*(const f32x4*)(&Gxs[idx]));
    if (lane < 32) ((float*)(bp + 1536))[lane] = csh[lane];
}

// ---------------- main scan: one 256-thread block (4 waves) per (batch, rowblk).
// R6 structure verbatim (best measured: 173.5 us). ONE change: XCD-aware block
// map batch = blockIdx & 15, so all 16 rowblk-blocks of a batch share
// blockIdx % 8 -> the SAME XCD L2. They run near-lockstep through the scan, so
// x[b] is fetched from HBM once per XCD instead of ~4x chip-wide, and every
// in-loop x/blob prefetch becomes an L2 hit (~200 cy) instead of an HBM miss
// (~900 cy) -- removing the exposed load latency from the loop-carried chain.
__global__ __launch_bounds__(256, 1) void ldm_main(
    const float* __restrict__ x,
    const float* __restrict__ Minit,
    const float* __restrict__ alpha_raw,
    const unsigned char* __restrict__ blob,
    float* __restrict__ out)
{
    const int tid    = threadIdx.x;
    const int lane   = tid & 63;
    const int w      = __builtin_amdgcn_readfirstlane(tid >> 6); // 0..3
    const int batch  = blockIdx.x & 15;       // XCD-aligned: blockIdx%8 == batch%8
    const int rowblk = blockIdx.x >> 4;
    const int l15    = lane & 15;
    const int q      = lane >> 4;
    const int col0   = w * 64;                // wave's 64-col slice

    __shared__ f32x4 parts[2][W_][2][64];     // [parity][wave][chunk][lane] = 16 KB

    const float alpha = 0.5f + 0.5f / (1.0f + expf(-alpha_raw[0]));
    const float a2 = alpha * alpha, a4 = a2 * a2, a8 = a4 * a4, a16 = a8 * a8;
    const float a32 = a16 * a16;
    const float aq = (q == 0) ? 1.f : (q == 1) ? a4 : (q == 2) ? a8 : a8 * a4;
    const f32x4 apowA = { aq, aq * alpha, aq * a2, aq * a2 * alpha };
    const f32x4 apowB = apowA * a16;

    // identity B-fragment for transpose MFMA
    const int s = l15 - (q << 2);
    bf16x4 IB;
    IB[0] = (s == 0) ? (short)0x3F80 : (short)0;
    IB[1] = (s == 1) ? (short)0x3F80 : (short)0;
    IB[2] = (s == 2) ? (short)0x3F80 : (short)0;
    IB[3] = (s == 3) ? (short)0x3F80 : (short)0;

    const int mrow = rowblk * 16 + l15;
    f32x4 master[4];                          // 16 rows x own 64 cols
    #pragma unroll
    for (int cb = 0; cb < 4; ++cb)
        master[cb] = *(const f32x4*)(Minit + (size_t)mrow * D_ + col0 + cb * 16 + q * 4);

    const float* xbb = x + (size_t)batch * S_ * D_;
    const unsigned char* bb0 = blob + (size_t)batch * NP_ * PBLOB_;
    const int tfoff = (l15 * 16 + q * 4) * 2;

    const float* xr = xbb + (size_t)l15 * D_ + col0 + q * 4;  // row l15, own col
    const float* xptr;
    const unsigned char* bptr;
    float* outpj = out + (size_t)batch * S_ * D_ + rowblk * 16 + l15
                 + (size_t)q * 4 * D_;        // chunk-a row base, pair 0

    struct BlobT { bf16x4 Ta, Tb, Gx; f32x4 ca, cb; };
    BlobT bA, bB;
    bf16x4 XA[8], XB[8];       // bf16 A-frags: [0..3]=chunk a, [4..7]=chunk b
    f32x4  Xf[8];              // next-pair f32 in flight (32 VGPR)
    const f32x4 zz = {0,0,0,0};

    {   // ---------------- prologue: pair 0
        #pragma unroll
        for (int cb = 0; cb < 4; ++cb) {
            Xf[cb]     = *(const f32x4*)(xr + cb * 16);
            Xf[4 + cb] = *(const f32x4*)(xr + 16 * D_ + cb * 16);
        }
        #pragma unroll
        for (int i = 0; i < 8; ++i) XA[i] = pk4(Xf[i]);
        bA.Ta = *(const bf16x4*)(bb0 + tfoff);
        bA.Tb = *(const bf16x4*)(bb0 + 512 + tfoff);
        bA.Gx = *(const bf16x4*)(bb0 + 1024 + tfoff);
        bA.ca = *(const f32x4*)(bb0 + 1536 + q * 16);
        bA.cb = *(const f32x4*)(bb0 + 1600 + q * 16);
        xptr = xr + 32 * D_;                  // -> X(1)
        bptr = bb0 + PBLOB_;                  // -> blob(1)
    }

    auto body = [&](int j, bf16x4 (&Xc)[8], bf16x4 (&Xn)[8], BlobT& bc, BlobT& bn) {
        const int par = j & 1;
        // prefetch pair j+1 (f32 X + blob); converted at body end
        #pragma unroll
        for (int cb = 0; cb < 4; ++cb) {
            Xf[cb]     = *(const f32x4*)(xptr + cb * 16);
            Xf[4 + cb] = *(const f32x4*)(xptr + 16 * D_ + cb * 16);
        }
        bn.Ta = *(const bf16x4*)(bptr + tfoff);
        bn.Tb = *(const bf16x4*)(bptr + 512 + tfoff);
        bn.Gx = *(const bf16x4*)(bptr + 1024 + tfoff);
        bn.ca = *(const f32x4*)(bptr + 1536 + q * 16);
        bn.cb = *(const f32x4*)(bptr + 1600 + q * 16);
        if (j < NP_ - 2) { xptr += 32 * D_; bptr += PBLOB_; }

        // retrieval partials over own 64 cols (4-deep C-chains, a/b independent)
        bf16x4 mf[4];
        #pragma unroll
        for (int cb = 0; cb < 4; ++cb) mf[cb] = pk4(master[cb]);
        f32x4 acca = zz, accb = zz;
        #pragma unroll
        for (int cb = 0; cb < 4; ++cb) {
            acca = mfma_bf16(Xc[cb],     mf[cb], acca);
            accb = mfma_bf16(Xc[4 + cb], mf[cb], accb);
        }
        parts[par][w][0][lane] = acca;
        parts[par][w][1][lane] = accb;

        // transpose frags (independent of master/reduce; fills pre-barrier)
        bf16x4 ta[4], tb[4];
        #pragma unroll
        for (int cb = 0; cb < 4; ++cb) {
            ta[cb] = pk4(mfma_bf16(Xc[cb],     IB, zz));
            tb[cb] = pk4(mfma_bf16(Xc[4 + cb], IB, zz));
        }
        __syncthreads();                      // the ONE barrier per pair

        // direct 4-partial reduce (every wave reads all partials)
        f32x4 pa0 = parts[par][0][0][lane], pa1 = parts[par][1][0][lane];
        f32x4 pa2 = parts[par][2][0][lane], pa3 = parts[par][3][0][lane];
        f32x4 pb0 = parts[par][0][1][lane], pb1 = parts[par][1][1][lane];
        f32x4 pb2 = parts[par][2][1][lane], pb3 = parts[par][3][1][lane];
        f32x4 bba = (pa0 + pa1) + (pa2 + pa3);
        f32x4 bbb = (pb0 + pb1) + (pb2 + pb3);

        // chunk a fixup: d_a = (I+T_a)*bb_a
        f32x4 da = mfma_bf16(bc.Ta, pk4(bba), bba);
        if (w == 2) {
            #pragma unroll
            for (int r = 0; r < 4; ++r) outpj[r * D_] = da[r] * apowA[r];
        }
        bf16x4 ea = pk4(da * bc.ca);
        // chunk b in-pair cross-correction + fixup
        f32x4 bb2 = mfma_bf16(bc.Gx, ea, bbb);
        f32x4 db = mfma_bf16(bc.Tb, pk4(bb2), bb2);
        if (w == 3) {
            #pragma unroll
            for (int r = 0; r < 4; ++r) outpj[(16 + r) * D_] = db[r] * apowB[r];
        }
        bf16x4 eb = pk4(db * bc.cb);

        // rank-32 update on own cols, then *alpha^32
        #pragma unroll
        for (int cb = 0; cb < 4; ++cb) {
            f32x4 m = mfma_bf16(ta[cb], ea, master[cb]);
            master[cb] = mfma_bf16(tb[cb], eb, m) * a32;
        }

        // convert next pair to bf16 (load->use distance ~ one full body)
        #pragma unroll
        for (int i = 0; i < 8; ++i) Xn[i] = pk4(Xf[i]);
        outpj += 32 * D_;
    };

    for (int j = 0; j < NP_; j += 2) {
        body(j,     XA, XB, bA, bB);
        body(j + 1, XB, XA, bB, bA);
    }

    // M_final -> second output region [B, D, D]
    float* Mout = out + (size_t)B_ * S_ * D_
                + ((size_t)batch * D_ + mrow) * D_;
    #pragma unroll
    for (int cb = 0; cb < 4; ++cb)
        *(f32x4*)(Mout + col0 + cb * 16 + q * 4) = master[cb];
}

extern "C" void kernel_launch(void* const* d_in, const int* in_sizes, int n_in,
                              void* d_out, int out_size, void* d_ws, size_t ws_size,
                              hipStream_t stream) {
    const float* x         = (const float*)d_in[0];
    const float* Minit     = (const float*)d_in[1];
    const float* eta_raw   = (const float*)d_in[2];
    const float* alpha_raw = (const float*)d_in[3];
    float* out = (float*)d_out;
    unsigned char* blob = (unsigned char*)d_ws;   // B_*NP_*1664 = 3.4 MB

    hipLaunchKernelGGL(ldm_prep, dim3(B_ * NP_), dim3(64), 0, stream,
                       x, eta_raw, alpha_raw, blob);
    hipLaunchKernelGGL(ldm_main, dim3(B_ * 16), dim3(256), 0, stream,
                       x, Minit, alpha_raw, blob, out);
}